// Round 5
// baseline (334.739 us; speedup 1.0000x reference)
//
#include <hip/hip_runtime.h>
#include <stdint.h>

// SIREN MLP 3->256->256->256->256->3, N=524288, fp32 in/out.
// Hidden layers: bf16 MFMA 16x16x32, D[chan][pt]. W streams global->VGPR via
// 2-kc-pair rotating double-buffer. h in LDS, conflict-free 16B-unit layout
// u = (kc*4+pt)*64 + q*16 + n16 within a 32KB pt-panel.
// R5 (246us): 4-wave/64-pt blocks, 12 waves/CU. R9 (260us): 8-wave blocks,
//   16 waves/CU -- occupancy +37% gained nothing => serial-sum pipe model:
//   dur ~= L2-W(219K) + LDS(145K) + VALU(85K) + MFMA(60K) cycles. Largest
//   term is the per-block L2 weight re-stream (every 64-pt block reads all
//   384KB of W1..W3).
// R10: 768-thread / 12-wave blocks = 3 pt-panels x 4 chan-waves, 192 pts
//   per block. Same per-wave tile as R5 (64c x 64p, acc 64, pair-dbuf 64,
//   live ~148 <= 170 @ 3 waves/EU). The 3 panel-waves sharing a chan range
//   load IDENTICAL W addresses in lockstep -> L1 dedup -> L2 W traffic
//   3.1GB -> ~1.05GB. LDS/VALU/matrix per point unchanged. h = 3x32KB=96KB.
//   Grid 2731, last block tail-clamped (x reads clamped, out stores guarded).

typedef float    f32x4 __attribute__((ext_vector_type(4)));
typedef short    s16x8 __attribute__((ext_vector_type(8)));
typedef uint32_t u32x2 __attribute__((ext_vector_type(2)));
typedef uint32_t u32x4 __attribute__((ext_vector_type(4)));

#define INV2PI 0.15915494309189535f
#define L0SCALE 4.774648292756860f   /* 30/(2*pi) */
#define W4OFF 196608                 /* halfword offset of W4^T frag in ws */
#define NPTS 524288
#define NBLK 2731                    /* ceil(524288 / 192) */

__device__ __forceinline__ uint16_t f32_to_bf16(float f) {
    uint32_t u = __builtin_bit_cast(uint32_t, f);
    u += 0x7FFFu + ((u >> 16) & 1u);   // RNE
    return (uint16_t)(u >> 16);
}
__device__ __forceinline__ uint32_t pack_bf16x2(float lo, float hi) {
#if __has_builtin(__builtin_amdgcn_cvt_pk_bf16_f32)
    auto v = __builtin_amdgcn_cvt_pk_bf16_f32(lo, hi);   // lo -> low half
    return __builtin_bit_cast(uint32_t, v);
#else
    uint32_t a = __builtin_bit_cast(uint32_t, lo);
    uint32_t b = __builtin_bit_cast(uint32_t, hi);
    a += 0x7FFFu + ((a >> 16) & 1u);
    b += 0x7FFFu + ((b >> 16) & 1u);
    return (a >> 16) | (b & 0xFFFF0000u);
#endif
}
// sin with input in REVOLUTIONS (v_sin_f32); 1/(2pi) pre-folded into weights.
__device__ __forceinline__ float sin_rev(float r) {
    return __builtin_amdgcn_sinf(r);
}

// W1..W3 -> bf16 A-frag order, scaled by 1/(2pi):
//   hw idx = (((l*8+kc)*16 + (c>>4))*64 + q*16 + (c&15))*8 + j, k=kc*32+q*8+j
// W4 (3x256) -> zero-padded B-frag (16 out-cols, 3 used), unscaled:
//   hw idx = W4OFF + (kc*64 + lane)*8 + j; value = n16<3 ? W4[n16][kc*32+q*8+j] : 0
__global__ void convert_weights(const float* __restrict__ W1,
                                const float* __restrict__ W2,
                                const float* __restrict__ W3,
                                const float* __restrict__ W4,
                                uint16_t* __restrict__ wsb) {
    int tid = blockIdx.x * blockDim.x + threadIdx.x;
    if (tid < 196608) {
        int l = tid >> 16;
        int r = tid & 65535;
        int c = r >> 8;        // out-chan
        int k = r & 255;       // in-chan
        const float* W = (l == 0) ? W1 : (l == 1) ? W2 : W3;
        int kc = k >> 5, q = (k >> 3) & 3, j = k & 7;
        wsb[(((l * 8 + kc) * 16 + (c >> 4)) * 64 + q * 16 + (c & 15)) * 8 + j] =
            f32_to_bf16(W[c * 256 + k] * INV2PI);
    } else if (tid < 200704) {
        int e = tid - 196608;              // 0..4095
        int kc = e >> 9, lane = (e >> 3) & 63, j = e & 7;
        int n16 = lane & 15, q = lane >> 4;
        float v = (n16 < 3) ? W4[n16 * 256 + kc * 32 + q * 8 + j] : 0.0f;
        wsb[W4OFF + (kc * 64 + lane) * 8 + j] = f32_to_bf16(v);
    }
}

// 768 threads = 12 waves = 3 pt-panels (pg) x 4 chan-waves (cw).
// Wave (pg,cw): pts pg*64..+63 of the block, chans cw*64..+63.
// (768,3): 3 waves/EU, reg cap 170; live set ~148 (64 acc + 64 Wbuf pair-dbuf
// + 16 hf + addressing) -- same shape as the proven R5 allocation.
__global__ __launch_bounds__(768, 3) void siren_main(
    const float* __restrict__ x,
    const float* __restrict__ W0, const float* __restrict__ b0,
    const float* __restrict__ b1, const float* __restrict__ b2,
    const float* __restrict__ b3,
    const float* __restrict__ b4,
    const uint16_t* __restrict__ Wb,   // permuted W1..W3 + W4 frag
    float* __restrict__ out)
{
    __shared__ uint16_t h_lds[3 * 16384];   // 96 KB: 3 pt-panels of 32 KB

    const int tid  = threadIdx.x;
    const int lane = tid & 63;
    const int wid  = tid >> 6;         // 0..11
    const int pg   = wid >> 2;         // pt-panel 0..2
    const int cw   = wid & 3;          // chan-wave 0..3
    const int n16  = lane & 15;
    const int q    = lane >> 4;
    const int p0   = blockIdx.x * 192;
    uint16_t* hp   = h_lds + pg * 16384;   // this wave's pt-panel

    // ------- Layer 0 (fp32): h1 = sin_rev( (30/2pi)*(W0 x + b0) ) ----------
    {
        float xv[4][3];
        #pragma unroll
        for (int rt = 0; rt < 4; ++rt) {
            int pidx = p0 + pg * 64 + rt * 16 + n16;
            if (pidx >= NPTS) pidx = NPTS - 1;      // tail clamp (dup, finite)
            const float* xp = x + pidx * 3;
            xv[rt][0] = xp[0]; xv[rt][1] = xp[1]; xv[rt][2] = xp[2];
        }
        #pragma unroll
        for (int oo = 0; oo < 2; ++oo) {
            const int octet = cw * 8 + oo * 4 + q;      // chan-octet 0..31
            const float* w0r = W0 + octet * 24;
            float wv[24];
            #pragma unroll
            for (int i = 0; i < 24; ++i) wv[i] = w0r[i] * L0SCALE;
            float bb[8];
            #pragma unroll
            for (int i = 0; i < 8; ++i) bb[i] = b0[octet * 8 + i] * L0SCALE;
            const int kc0 = octet >> 2, q0 = octet & 3;
            #pragma unroll
            for (int rt = 0; rt < 4; ++rt) {
                u32x4 pk;
                #pragma unroll
                for (int j2 = 0; j2 < 4; ++j2) {
                    float za = wv[(2*j2  )*3+0] * xv[rt][0] +
                               wv[(2*j2  )*3+1] * xv[rt][1] +
                               wv[(2*j2  )*3+2] * xv[rt][2] + bb[2*j2];
                    float zb = wv[(2*j2+1)*3+0] * xv[rt][0] +
                               wv[(2*j2+1)*3+1] * xv[rt][1] +
                               wv[(2*j2+1)*3+2] * xv[rt][2] + bb[2*j2+1];
                    pk[j2] = pack_bf16x2(sin_rev(za), sin_rev(zb));
                }
                *(u32x4*)&hp[((kc0 * 4 + rt) * 64 + q0 * 16 + n16) * 8] = pk;
            }
        }
    }
    __syncthreads();

    // ------- Hidden layers (bf16 MFMA, D[chan][pt]) -------------------------
    #pragma unroll
    for (int l = 0; l < 3; ++l) {
        const uint16_t* wsl = Wb + l * 65536;
        const float* bl = (l == 0) ? b1 : (l == 1) ? b2 : b3;

        // rotating kc-pair double buffer of W fragments (256B -> SSA).
        // The 3 pg-waves with equal cw issue IDENTICAL addresses right after
        // the same barrier -> L1 serves 2 of 3 -> L2 sees ~1/3 the traffic.
        s16x8 Wbuf[2][2][4];   // [buf][kc-in-pair][chan-tile]
        #pragma unroll
        for (int kc2 = 0; kc2 < 2; ++kc2)
            #pragma unroll
            for (int t = 0; t < 4; ++t)
                Wbuf[0][kc2][t] = *(const s16x8*)(wsl + ((kc2 * 16 + cw * 4 + t) * 64 + lane) * 8);

        // acc init = bias (pre-scaled): rides the MFMA C input, no epilogue add
        f32x4 acc[4][4];       // [chan-tile t][pt-tile pt]
        #pragma unroll
        for (int t = 0; t < 4; ++t) {
            f32x4 bv = *(const f32x4*)&bl[cw * 64 + t * 16 + q * 4];
            bv *= INV2PI;
            #pragma unroll
            for (int pt = 0; pt < 4; ++pt) acc[t][pt] = bv;
        }

        #pragma unroll
        for (int kp = 0; kp < 4; ++kp) {      // kc pair index
            const int cur = kp & 1, nxt = cur ^ 1;
            if (kp < 3) {                     // prefetch next pair under MFMA
                #pragma unroll
                for (int kc2 = 0; kc2 < 2; ++kc2)
                    #pragma unroll
                    for (int t = 0; t < 4; ++t)
                        Wbuf[nxt][kc2][t] = *(const s16x8*)(wsl +
                            (((kp * 2 + 2 + kc2) * 16 + cw * 4 + t) * 64 + lane) * 8);
            }
            #pragma unroll
            for (int kc2 = 0; kc2 < 2; ++kc2) {
                const int kc = kp * 2 + kc2;
                s16x8 hf[4];   // B-frags: lane n16 = pt-in-tile, q = k-octet
                #pragma unroll
                for (int pt = 0; pt < 4; ++pt)
                    hf[pt] = *(const s16x8*)&hp[((kc * 4 + pt) * 64 + lane) * 8];
                #pragma unroll
                for (int t = 0; t < 4; ++t)
                    #pragma unroll
                    for (int pt = 0; pt < 4; ++pt)
                        acc[t][pt] = __builtin_amdgcn_mfma_f32_16x16x32_bf16(
                            Wbuf[cur][kc2][t], hf[pt], acc[t][pt], 0, 0, 0);
            }
        }
        __syncthreads();   // all h reads done before overwrite

        // epilogue: sin (bias already in acc), write h_next in B-frag layout
        // into this wave's panel. chan c = cw*64 + t*16 + q*4 + r:
        // kcp = cw*2 + (t>>1), qp = (t*2 + (q>>1)) & 3, j = (q&1)*4 + r.
        uint32_t* hw = (uint32_t*)h_lds;
        #pragma unroll
        for (int t = 0; t < 4; ++t) {
            const int kcp = cw * 2 + (t >> 1);
            const int qp  = (t * 2 + (q >> 1)) & 3;
            #pragma unroll
            for (int pt = 0; pt < 4; ++pt) {
                float s0 = sin_rev(acc[t][pt][0]);
                float s1 = sin_rev(acc[t][pt][1]);
                float s2 = sin_rev(acc[t][pt][2]);
                float s3 = sin_rev(acc[t][pt][3]);
                int base = pg * 8192 +
                           ((kcp * 4 + pt) * 64 + qp * 16 + n16) * 4 + (q & 1) * 2;
                u32x2 w2 = { pack_bf16x2(s0, s1), pack_bf16x2(s2, s3) };
                *(u32x2*)&hw[base] = w2;   // 8B write, r=0..3
            }
        }
        __syncthreads();
    }

    // ------- Final layer via MFMA: out = W4 h4 + b4 -------------------------
    // 12 pt-tiles of 16 pts; wave (pg,cw) takes tile cw of panel pg.
    {
        float bb4 = (n16 < 3) ? b4[n16] : 0.0f;
        f32x4 accF = { bb4, bb4, bb4, bb4 };
        #pragma unroll
        for (int kc = 0; kc < 8; ++kc) {
            s16x8 w4f = *(const s16x8*)(Wb + W4OFF + (kc * 64 + lane) * 8);
            s16x8 af  = *(const s16x8*)&hp[((kc * 4 + cw) * 64 + lane) * 8];
            accF = __builtin_amdgcn_mfma_f32_16x16x32_bf16(af, w4f, accF, 0, 0, 0);
        }
        // D: row=q*4+r -> pt-in-tile, col=n16 -> out-chan (3 used)
        if (n16 < 3) {
            #pragma unroll
            for (int r = 0; r < 4; ++r) {
                int p = p0 + pg * 64 + cw * 16 + q * 4 + r;
                if (p < NPTS) out[p * 3 + n16] = accF[r];
            }
        }
    }
}

extern "C" void kernel_launch(void* const* d_in, const int* in_sizes, int n_in,
                              void* d_out, int out_size, void* d_ws, size_t ws_size,
                              hipStream_t stream) {
    const float* x  = (const float*)d_in[0];
    const float* W0 = (const float*)d_in[1];
    const float* b0 = (const float*)d_in[2];
    const float* W1 = (const float*)d_in[3];
    const float* b1 = (const float*)d_in[4];
    const float* W2 = (const float*)d_in[5];
    const float* b2 = (const float*)d_in[6];
    const float* W3 = (const float*)d_in[7];
    const float* b3 = (const float*)d_in[8];
    const float* W4 = (const float*)d_in[9];
    const float* b4 = (const float*)d_in[10];
    float* outp     = (float*)d_out;
    uint16_t* wsb   = (uint16_t*)d_ws;   // needs 402 KB

    hipLaunchKernelGGL(convert_weights, dim3(784), dim3(256), 0, stream,
                       W1, W2, W3, W4, wsb);
    hipLaunchKernelGGL(siren_main, dim3(NBLK), dim3(768), 0, stream,
                       x, W0, b0, b1, b2, b3, b4, wsb, outp);
}

// Round 6
// 307.008 us; speedup vs baseline: 1.0903x; 1.0903x over previous
//
#include <hip/hip_runtime.h>
#include <stdint.h>

// SIREN MLP 3->256->256->256->256->3, N=524288, fp32 in/out.
// Hidden layers: bf16 MFMA 16x16x32, D[chan][pt]. W streams global->VGPR via
// 2-kc-pair rotating double-buffer. h ping-pongs in 32KB LDS, conflict-free
// 16B-unit layout u=(kc*4+pt)*64+q*16+n16.
// Evidence so far: dur ~= 517K + 214K/groups cycles (R10 1grp=731K,
//   R9 2grp=624K, R5 3grp=590K). LDS-read doubling (R9) and L2-byte cut
//   (R10) had no effect outside the law -> the 1/g term is the barrier
//   vmcnt(0) drain (__syncthreads) killing the W-prefetch pipeline 7x/block;
//   other resident blocks partially cover it.
// R11 (this): back to R5's 3-group structure, but
//   (a) all barriers become "s_waitcnt lgkmcnt(0); s_barrier" (single asm) --
//       LDS-correct, W global loads stay IN FLIGHT across barriers;
//   (b) unbroken W pipeline: layer-1 pair hoisted above L0, next-layer pair
//       prefetched in the idle kp==3 dbuf slot, W4 frags prefetched at
//       l==2/kp==3 into the same slot. Zero register growth vs R5.

typedef float    f32x4 __attribute__((ext_vector_type(4)));
typedef short    s16x8 __attribute__((ext_vector_type(8)));
typedef uint32_t u32x2 __attribute__((ext_vector_type(2)));
typedef uint32_t u32x4 __attribute__((ext_vector_type(4)));

#define INV2PI 0.15915494309189535f
#define L0SCALE 4.774648292756860f   /* 30/(2*pi) */
#define W4OFF 196608                 /* halfword offset of W4^T frag in ws */

// LDS-only barrier: orders ds ops (lgkmcnt) but does NOT drain vmcnt, so the
// global W-prefetch stream survives the barrier (verified mechanism of the
// 8-phase template, m194-m201). Single asm so nothing schedules in between.
#define SYNC_LDS() asm volatile("s_waitcnt lgkmcnt(0)\n\ts_barrier" ::: "memory")

__device__ __forceinline__ uint16_t f32_to_bf16(float f) {
    uint32_t u = __builtin_bit_cast(uint32_t, f);
    u += 0x7FFFu + ((u >> 16) & 1u);   // RNE
    return (uint16_t)(u >> 16);
}
__device__ __forceinline__ uint32_t pack_bf16x2(float lo, float hi) {
#if __has_builtin(__builtin_amdgcn_cvt_pk_bf16_f32)
    auto v = __builtin_amdgcn_cvt_pk_bf16_f32(lo, hi);   // lo -> low half
    return __builtin_bit_cast(uint32_t, v);
#else
    uint32_t a = __builtin_bit_cast(uint32_t, lo);
    uint32_t b = __builtin_bit_cast(uint32_t, hi);
    a += 0x7FFFu + ((a >> 16) & 1u);
    b += 0x7FFFu + ((b >> 16) & 1u);
    return (a >> 16) | (b & 0xFFFF0000u);
#endif
}
// sin with input in REVOLUTIONS (v_sin_f32); 1/(2pi) pre-folded into weights.
__device__ __forceinline__ float sin_rev(float r) {
    return __builtin_amdgcn_sinf(r);
}

// W1..W3 -> bf16 A-frag order, scaled by 1/(2pi):
//   hw idx = (((l*8+kc)*16 + (c>>4))*64 + q*16 + (c&15))*8 + j, k=kc*32+q*8+j
// W4 (3x256) -> zero-padded B-frag (16 out-cols, 3 used), unscaled:
//   hw idx = W4OFF + (kc*64 + lane)*8 + j; value = n16<3 ? W4[n16][kc*32+q*8+j] : 0
__global__ void convert_weights(const float* __restrict__ W1,
                                const float* __restrict__ W2,
                                const float* __restrict__ W3,
                                const float* __restrict__ W4,
                                uint16_t* __restrict__ wsb) {
    int tid = blockIdx.x * blockDim.x + threadIdx.x;
    if (tid < 196608) {
        int l = tid >> 16;
        int r = tid & 65535;
        int c = r >> 8;        // out-chan
        int k = r & 255;       // in-chan
        const float* W = (l == 0) ? W1 : (l == 1) ? W2 : W3;
        int kc = k >> 5, q = (k >> 3) & 3, j = k & 7;
        wsb[(((l * 8 + kc) * 16 + (c >> 4)) * 64 + q * 16 + (c & 15)) * 8 + j] =
            f32_to_bf16(W[c * 256 + k] * INV2PI);
    } else if (tid < 200704) {
        int e = tid - 196608;              // 0..4095
        int kc = e >> 9, lane = (e >> 3) & 63, j = e & 7;
        int n16 = lane & 15, q = lane >> 4;
        float v = (n16 < 3) ? W4[n16 * 256 + kc * 32 + q * 8 + j] : 0.0f;
        wsb[W4OFF + (kc * 64 + lane) * 8 + j] = f32_to_bf16(v);
    }
}

// 256 threads = 4 waves, 64 points/block. Wave wid owns chans wid*64..+63.
// (256,3): 3 waves/EU -> 3 blocks/CU; unified VGPR+acc budget 170/wave,
// live set ~148+8 (same shape as the proven R5 allocation).
__global__ __launch_bounds__(256, 3) void siren_main(
    const float* __restrict__ x,
    const float* __restrict__ W0, const float* __restrict__ b0,
    const float* __restrict__ b1, const float* __restrict__ b2,
    const float* __restrict__ b3,
    const float* __restrict__ b4,
    const uint16_t* __restrict__ Wb,   // permuted W1..W3 + W4 frag
    float* __restrict__ out)
{
    __shared__ uint16_t h_lds[2048 * 8];   // 32 KB

    const int tid  = threadIdx.x;
    const int lane = tid & 63;
    const int wid  = tid >> 6;
    const int n16  = lane & 15;
    const int q    = lane >> 4;
    const int p0   = blockIdx.x * 64;

    // W fragment rotating buffer — lives across the whole kernel so the
    // global-load pipeline is never broken by a barrier.
    s16x8 Wbuf[2][2][4];   // [buf][kc-in-pair][chan-tile]

    // Issue layer-1's first kc-pair NOW; latency hides under L0 compute.
    #pragma unroll
    for (int kc2 = 0; kc2 < 2; ++kc2)
        #pragma unroll
        for (int t = 0; t < 4; ++t)
            Wbuf[0][kc2][t] = *(const s16x8*)(Wb + ((kc2 * 16 + wid * 4 + t) * 64 + lane) * 8);

    // b4 pre-load (1 reg, used at the very end).
    const float bb4 = (n16 < 3) ? b4[n16] : 0.0f;

    // ------- Layer 0 (fp32): h1 = sin_rev( (30/2pi)*(W0 x + b0) ) ----------
    {
        float xv[4][3];
        #pragma unroll
        for (int rt = 0; rt < 4; ++rt) {
            const float* xp = x + (p0 + rt * 16 + n16) * 3;
            xv[rt][0] = xp[0]; xv[rt][1] = xp[1]; xv[rt][2] = xp[2];
        }
        #pragma unroll
        for (int oo = 0; oo < 2; ++oo) {
            const int octet = wid * 8 + oo * 4 + q;      // chan-octet 0..31
            const float* w0r = W0 + octet * 24;
            float wv[24];
            #pragma unroll
            for (int i = 0; i < 24; ++i) wv[i] = w0r[i] * L0SCALE;
            float bb[8];
            #pragma unroll
            for (int i = 0; i < 8; ++i) bb[i] = b0[octet * 8 + i] * L0SCALE;
            const int kc0 = octet >> 2, q0 = octet & 3;
            #pragma unroll
            for (int rt = 0; rt < 4; ++rt) {
                u32x4 pk;
                #pragma unroll
                for (int j2 = 0; j2 < 4; ++j2) {
                    float za = wv[(2*j2  )*3+0] * xv[rt][0] +
                               wv[(2*j2  )*3+1] * xv[rt][1] +
                               wv[(2*j2  )*3+2] * xv[rt][2] + bb[2*j2];
                    float zb = wv[(2*j2+1)*3+0] * xv[rt][0] +
                               wv[(2*j2+1)*3+1] * xv[rt][1] +
                               wv[(2*j2+1)*3+2] * xv[rt][2] + bb[2*j2+1];
                    pk[j2] = pack_bf16x2(sin_rev(za), sin_rev(zb));
                }
                *(u32x4*)&h_lds[((kc0 * 4 + rt) * 64 + q0 * 16 + n16) * 8] = pk;
            }
        }
    }
    SYNC_LDS();

    // ------- Hidden layers (bf16 MFMA, D[chan][pt]) -------------------------
    #pragma unroll
    for (int l = 0; l < 3; ++l) {
        const uint16_t* wsl = Wb + l * 65536;
        const float* bl = (l == 0) ? b1 : (l == 1) ? b2 : b3;

        // acc init = bias (pre-scaled): rides the MFMA C input, no epilogue add
        f32x4 acc[4][4];       // [chan-tile t][pt-tile pt]
        #pragma unroll
        for (int t = 0; t < 4; ++t) {
            f32x4 bv = *(const f32x4*)&bl[wid * 64 + t * 16 + q * 4];
            bv *= INV2PI;
            #pragma unroll
            for (int pt = 0; pt < 4; ++pt) acc[t][pt] = bv;
        }

        #pragma unroll
        for (int kp = 0; kp < 4; ++kp) {      // kc pair index
            const int cur = kp & 1, nxt = cur ^ 1;
            if (kp < 3) {                     // prefetch next pair under MFMA
                #pragma unroll
                for (int kc2 = 0; kc2 < 2; ++kc2)
                    #pragma unroll
                    for (int t = 0; t < 4; ++t)
                        Wbuf[nxt][kc2][t] = *(const s16x8*)(wsl +
                            (((kp * 2 + 2 + kc2) * 16 + wid * 4 + t) * 64 + lane) * 8);
            } else if (l < 2) {
                // idle dbuf slot: prefetch NEXT layer's first kc-pair; the
                // loads fly across the two lgkm-only barriers below.
                const uint16_t* wsn = Wb + (l + 1) * 65536;
                #pragma unroll
                for (int kc2 = 0; kc2 < 2; ++kc2)
                    #pragma unroll
                    for (int t = 0; t < 4; ++t)
                        Wbuf[nxt][kc2][t] = *(const s16x8*)(wsn +
                            ((kc2 * 16 + wid * 4 + t) * 64 + lane) * 8);
            } else {
                // l==2: prefetch the 8 W4^T frags into the idle slot
                // (kc = kc2*4 + t), consumed register-resident at the end.
                #pragma unroll
                for (int kc2 = 0; kc2 < 2; ++kc2)
                    #pragma unroll
                    for (int t = 0; t < 4; ++t)
                        Wbuf[nxt][kc2][t] = *(const s16x8*)(Wb + W4OFF +
                            (((kc2 * 4 + t) * 64 + lane) * 8));
            }
            #pragma unroll
            for (int kc2 = 0; kc2 < 2; ++kc2) {
                const int kc = kp * 2 + kc2;
                s16x8 hf[4];   // B-frags: lane n16 = pt-in-tile, q = k-octet
                #pragma unroll
                for (int pt = 0; pt < 4; ++pt)
                    hf[pt] = *(const s16x8*)&h_lds[((kc * 4 + pt) * 64 + lane) * 8];
                #pragma unroll
                for (int t = 0; t < 4; ++t)
                    #pragma unroll
                    for (int pt = 0; pt < 4; ++pt)
                        acc[t][pt] = __builtin_amdgcn_mfma_f32_16x16x32_bf16(
                            Wbuf[cur][kc2][t], hf[pt], acc[t][pt], 0, 0, 0);
            }
        }
        SYNC_LDS();   // all h reads done before overwrite (lgkm only)

        // epilogue: sin (bias already in acc), write h_next in B-frag layout
        uint32_t* hw = (uint32_t*)h_lds;
        #pragma unroll
        for (int t = 0; t < 4; ++t) {
            const int kcp = wid * 2 + (t >> 1);
            const int qp  = (t * 2 + (q >> 1)) & 3;
            #pragma unroll
            for (int pt = 0; pt < 4; ++pt) {
                float s0 = sin_rev(acc[t][pt][0]);
                float s1 = sin_rev(acc[t][pt][1]);
                float s2 = sin_rev(acc[t][pt][2]);
                float s3 = sin_rev(acc[t][pt][3]);
                int base = ((kcp * 4 + pt) * 64 + qp * 16 + n16) * 4 + (q & 1) * 2;
                u32x2 w2 = { pack_bf16x2(s0, s1), pack_bf16x2(s2, s3) };
                *(u32x2*)&hw[base] = w2;   // 8B write, r=0..3
            }
        }
        SYNC_LDS();   // h_next visible to all waves (lgkm only)
    }

    // ------- Final layer via MFMA: out = W4 h4 + b4 -------------------------
    // W4^T frags already register-resident in Wbuf[0] (prefetched at l==2).
    {
        f32x4 accF = { bb4, bb4, bb4, bb4 };
        #pragma unroll
        for (int kc = 0; kc < 8; ++kc) {
            s16x8 af = *(const s16x8*)&h_lds[((kc * 4 + wid) * 64 + lane) * 8];
            accF = __builtin_amdgcn_mfma_f32_16x16x32_bf16(
                af, Wbuf[0][kc >> 2][kc & 3], accF, 0, 0, 0);
        }
        // D: row=q*4+r -> pt-in-tile (tile wid), col=n16 -> out-chan (3 used)
        if (n16 < 3) {
            #pragma unroll
            for (int r = 0; r < 4; ++r)
                out[(p0 + wid * 16 + q * 4 + r) * 3 + n16] = accF[r];
        }
    }
}

extern "C" void kernel_launch(void* const* d_in, const int* in_sizes, int n_in,
                              void* d_out, int out_size, void* d_ws, size_t ws_size,
                              hipStream_t stream) {
    const float* x  = (const float*)d_in[0];
    const float* W0 = (const float*)d_in[1];
    const float* b0 = (const float*)d_in[2];
    const float* W1 = (const float*)d_in[3];
    const float* b1 = (const float*)d_in[4];
    const float* W2 = (const float*)d_in[5];
    const float* b2 = (const float*)d_in[6];
    const float* W3 = (const float*)d_in[7];
    const float* b3 = (const float*)d_in[8];
    const float* W4 = (const float*)d_in[9];
    const float* b4 = (const float*)d_in[10];
    float* outp     = (float*)d_out;
    uint16_t* wsb   = (uint16_t*)d_ws;   // needs 402 KB

    hipLaunchKernelGGL(convert_weights, dim3(784), dim3(256), 0, stream,
                       W1, W2, W3, W4, wsb);
    hipLaunchKernelGGL(siren_main, dim3(8192), dim3(256), 0, stream,
                       x, W0, b0, b1, b2, b3, b4, wsb, outp);
}